// Round 1
// baseline (210.508 us; speedup 1.0000x reference)
//
#include <hip/hip_runtime.h>
#include <hip/hip_bf16.h>

// Fully-fused pipeline. B=1024, IN=768, HID=512, OUT=256.
// One block = 32 batch rows = the whole per-row pipeline:
//   P1: t = s_emb @ W1^T + b1        -> LDS t_s[32][512] fp32
//   P2: moments p_k, m_k (k=0..7)    -> LDS mom[32][16]  (pre-scaled by 1/k!)
//   P3: c = combin @ W2^T + b2       -> LDS (reuses t_s)
//   P3.5: Horner num/den, relu       -> o2 bf16 (global ws, own rows only)
//   P4: out = o2 @ W3^T + b3         -> global
// GEMMs: 32x32x16 bf16 MFMA, fragments loaded DIRECTLY from global in
// fragment order (row=lane&31, khalf=lane>>5, 8 contiguous k) — the old
// LDS staging was just a lane permutation of these same loads.
// Each wave owns whole N-tiles (no K-split -> no cross-wave reduction).

#define B_SZ 1024
#define HID 512
#define IN_D 768
#define OUT_D 256
#define NK 8

typedef float floatx16 __attribute__((ext_vector_type(16)));
typedef short short8  __attribute__((ext_vector_type(8)));

// round-half-up fp32->bf16 pair pack (low16 = a, high16 = b)
__device__ __forceinline__ unsigned pack_bf16(float a, float b) {
    unsigned ua = __float_as_uint(a) + 0x8000u;
    unsigned ub = __float_as_uint(b) + 0x8000u;
    return __builtin_amdgcn_perm(ub, ua, 0x07060302);
}
__device__ __forceinline__ uint4 pack8(float4 lo, float4 hi) {
    uint4 v;
    v.x = pack_bf16(lo.x, lo.y); v.y = pack_bf16(lo.z, lo.w);
    v.z = pack_bf16(hi.x, hi.y); v.w = pack_bf16(hi.z, hi.w);
    return v;
}

// One wave computes TWO 32x32 output tiles (cols w*64 .. w*64+63) over the
// full K, accumulating in registers; writes acc+bias to LDS in fp32.
template<int NCH>
__device__ __forceinline__ void gemm2_to_lds(
    const float* __restrict__ A, const int K,
    const float* __restrict__ W, const float* __restrict__ bias,
    const int row0, const int w, const int lane,
    float (*__restrict__ outL)[HID])
{
    const int m   = lane & 31;
    const int kh  = lane >> 5;
    const int n0a = w * 64, n0b = n0a + 32;

    const float* pa  = A + (size_t)(row0 + m) * K + kh * 8;
    const float* pba = W + (size_t)(n0a + m) * K + kh * 8;
    const float* pbb = W + (size_t)(n0b + m) * K + kh * 8;

    float4 a0 = *(const float4*)pa,  a1 = *(const float4*)(pa + 4);
    float4 u0 = *(const float4*)pba, u1 = *(const float4*)(pba + 4);
    float4 v0 = *(const float4*)pbb, v1 = *(const float4*)(pbb + 4);

    floatx16 acc0 = {}, acc1 = {};

    #pragma unroll 8
    for (int it = 0; it < NCH - 1; ++it) {
        uint4 af  = pack8(a0, a1);
        uint4 bfa = pack8(u0, u1);
        uint4 bfb = pack8(v0, v1);
        pa += 16; pba += 16; pbb += 16;
        a0 = *(const float4*)pa;  a1 = *(const float4*)(pa + 4);
        u0 = *(const float4*)pba; u1 = *(const float4*)(pba + 4);
        v0 = *(const float4*)pbb; v1 = *(const float4*)(pbb + 4);
        acc0 = __builtin_amdgcn_mfma_f32_32x32x16_bf16(
            *(short8*)&af, *(short8*)&bfa, acc0, 0, 0, 0);
        acc1 = __builtin_amdgcn_mfma_f32_32x32x16_bf16(
            *(short8*)&af, *(short8*)&bfb, acc1, 0, 0, 0);
    }
    {   // last chunk (no over-read)
        uint4 af  = pack8(a0, a1);
        uint4 bfa = pack8(u0, u1);
        uint4 bfb = pack8(v0, v1);
        acc0 = __builtin_amdgcn_mfma_f32_32x32x16_bf16(
            *(short8*)&af, *(short8*)&bfa, acc0, 0, 0, 0);
        acc1 = __builtin_amdgcn_mfma_f32_32x32x16_bf16(
            *(short8*)&af, *(short8*)&bfb, acc1, 0, 0, 0);
    }

    const float bva = bias[n0a + m], bvb = bias[n0b + m];
    // C/D layout (m74/m101): col = lane&31, row = (q&3)+8*(q>>2)+4*(lane>>5)
    #pragma unroll
    for (int q = 0; q < 16; ++q) {
        const int rr = (q & 3) + 8 * (q >> 2) + 4 * kh;
        outL[rr][n0a + m] = acc0[q] + bva;   // 2-way bank alias = free
        outL[rr][n0b + m] = acc1[q] + bvb;
    }
}

__global__ __launch_bounds__(512) void fused_k(
    const float* __restrict__ combin, const float* __restrict__ s_emb,
    const float* __restrict__ W1, const float* __restrict__ b1,
    const float* __restrict__ W2, const float* __restrict__ b2,
    const float* __restrict__ W3, const float* __restrict__ b3,
    unsigned* __restrict__ o2u, float* __restrict__ out)
{
    __shared__ float t_s[32][HID];      // 64 KB; t in P1/P2, c in P3/P3.5
    __shared__ float mom[32][2 * NK];   // 2 KB; [row][p0..p7, m0..m7] * 1/k!

    const int tid  = threadIdx.x;
    const int w    = tid >> 6;
    const int lane = tid & 63;
    const int row0 = blockIdx.x * 32;

    // ---------- P1: t = s_emb @ W1^T + b1 -> t_s ----------
    gemm2_to_lds<HID / 16>(s_emb, HID, W1, b1, row0, w, lane, t_s);
    __syncthreads();

    // ---------- P2: moments. wave w owns rows 4w..4w+3 ----------
    {
        const float invf[NK] = {1.f, 1.f, 0.5f, 1.f / 6.f, 1.f / 24.f,
                                1.f / 120.f, 1.f / 720.f, 1.f / 5040.f};
        #pragma unroll
        for (int r4 = 0; r4 < 4; ++r4) {
            const int r = (w << 2) + r4;
            const float* tp4 = &t_s[r][lane * 8];            // conflict-free
            float4 t0 = *(const float4*)tp4, t1 = *(const float4*)(tp4 + 4);
            const float* vp = s_emb + (size_t)(row0 + r) * HID + lane * 8;
            float4 v0 = *(const float4*)vp, v1 = *(const float4*)(vp + 4);
            const float te[8] = {t0.x, t0.y, t0.z, t0.w, t1.x, t1.y, t1.z, t1.w};
            const float ve[8] = {v0.x, v0.y, v0.z, v0.w, v1.x, v1.y, v1.z, v1.w};
            float p[NK] = {}, mm[NK] = {};
            #pragma unroll
            for (int e = 0; e < 8; ++e) {
                float tp = 1.f;
                #pragma unroll
                for (int k = 0; k < NK; ++k) {
                    p[k] += tp;
                    mm[k] = fmaf(tp, ve[e], mm[k]);
                    tp *= te[e];
                }
            }
            #pragma unroll
            for (int off = 1; off < 64; off <<= 1) {
                #pragma unroll
                for (int k = 0; k < NK; ++k) {
                    p[k]  += __shfl_xor(p[k], off);
                    mm[k] += __shfl_xor(mm[k], off);
                }
            }
            if (lane == 0) {
                #pragma unroll
                for (int k = 0; k < NK; ++k) {
                    mom[r][k]      = p[k]  * invf[k];
                    mom[r][NK + k] = mm[k] * invf[k];
                }
            }
        }
    }
    __syncthreads();   // mom visible; t_s free for reuse

    // ---------- P3: c = combin @ W2^T + b2 -> t_s (as c_s) ----------
    gemm2_to_lds<IN_D / 16>(combin, IN_D, W2, b2, row0, w, lane, t_s);
    __syncthreads();

    // ---------- P3.5: Horner softmax-ratio, relu -> o2 (bf16, global) ----
    {
        const float scale = 0.04419417382415922f;  // 1/sqrt(512)
        #pragma unroll
        for (int r4 = 0; r4 < 4; ++r4) {
            const int r = (w << 2) + r4;
            float cp[NK], cm[NK];
            #pragma unroll
            for (int k = 0; k < NK; ++k) {          // broadcast reads (free)
                cp[k] = mom[r][k];
                cm[k] = mom[r][NK + k];
            }
            const float* cptr = &t_s[r][lane * 8];
            float4 c0 = *(const float4*)cptr, c1 = *(const float4*)(cptr + 4);
            const float ce[8] = {c0.x, c0.y, c0.z, c0.w, c1.x, c1.y, c1.z, c1.w};
            float rres[8];
            #pragma unroll
            for (int e = 0; e < 8; ++e) {
                const float a = scale * ce[e];
                float n = cm[NK - 1], d = cp[NK - 1];
                #pragma unroll
                for (int k = NK - 2; k >= 0; --k) {
                    n = fmaf(n, a, cm[k]);
                    d = fmaf(d, a, cp[k]);
                }
                float rr = n * __builtin_amdgcn_rcpf(d);
                rres[e] = rr > 0.f ? rr : 0.f;
            }
            uint4 pk;
            pk.x = pack_bf16(rres[0], rres[1]);
            pk.y = pack_bf16(rres[2], rres[3]);
            pk.z = pack_bf16(rres[4], rres[5]);
            pk.w = pack_bf16(rres[6], rres[7]);
            // coalesced: 64 lanes x 16B contiguous per row
            *(uint4*)&o2u[(size_t)(row0 + r) * (HID / 2) + lane * 4] = pk;
        }
    }
    __syncthreads();   // implies vmcnt(0) drain before barrier -> o2 visible

    // ---------- P4: out = o2 @ W3^T + b3. wave w -> cols w*32..w*32+31 ----
    {
        const int m  = lane & 31;
        const int kh = lane >> 5;
        const int n0 = w * 32;
        const __hip_bfloat16* o2b = (const __hip_bfloat16*)o2u;

        const __hip_bfloat16* pa = o2b + (size_t)(row0 + m) * HID + kh * 8;
        const float* pb = W3 + (size_t)(n0 + m) * HID + kh * 8;

        uint4 av = *(const uint4*)pa;
        float4 u0 = *(const float4*)pb, u1 = *(const float4*)(pb + 4);
        floatx16 acc = {};

        #pragma unroll 8
        for (int it = 0; it < HID / 16 - 1; ++it) {
            uint4 af = av;
            uint4 bf = pack8(u0, u1);
            pa += 16; pb += 16;
            av = *(const uint4*)pa;
            u0 = *(const float4*)pb; u1 = *(const float4*)(pb + 4);
            acc = __builtin_amdgcn_mfma_f32_32x32x16_bf16(
                *(short8*)&af, *(short8*)&bf, acc, 0, 0, 0);
        }
        {
            uint4 bf = pack8(u0, u1);
            acc = __builtin_amdgcn_mfma_f32_32x32x16_bf16(
                *(short8*)&av, *(short8*)&bf, acc, 0, 0, 0);
        }

        const float bv = b3[n0 + m];
        float* ob = out + (size_t)row0 * OUT_D + n0 + m;
        #pragma unroll
        for (int q = 0; q < 16; ++q) {
            const int rr = (q & 3) + 8 * (q >> 2) + 4 * kh;
            ob[(size_t)rr * OUT_D] = acc[q] + bv;   // 128B coalesced / half-wave
        }
    }
}

extern "C" void kernel_launch(void* const* d_in, const int* in_sizes, int n_in,
                              void* d_out, int out_size, void* d_ws, size_t ws_size,
                              hipStream_t stream)
{
    const float* combin = (const float*)d_in[0];
    const float* s_emb  = (const float*)d_in[1];
    const float* W1     = (const float*)d_in[2];
    const float* b1     = (const float*)d_in[3];
    const float* W2     = (const float*)d_in[4];
    const float* b2     = (const float*)d_in[5];
    const float* W3     = (const float*)d_in[6];
    const float* b3     = (const float*)d_in[7];
    float* out = (float*)d_out;

    unsigned* o2u = (unsigned*)d_ws;   // [B, HID] bf16 = 1 MB of workspace

    fused_k<<<B_SZ / 32, 512, 0, stream>>>(combin, s_emb, W1, b1, W2, b2,
                                           W3, b3, o2u, out);
}

// Round 2
// 98.322 us; speedup vs baseline: 2.1410x; 2.1410x over previous
//
#include <hip/hip_runtime.h>
#include <hip/hip_bf16.h>

// B=1024, IN=768, HID=512, OUT=256
//   c = combin @ W2^T + b2   [1024,512] K=768   (bf16 MFMA)
//   t = s_emb  @ W1^T + b1   [1024,512] K=512   (fused launch)
//   o2[b,i] = relu(Taylor-softmax ratio)        (moments trick, deg-7)
//   out = o2 @ W3^T + b3     [1024,256] K=512
//
// GEMM: 32x32 tile/block, 4 waves K-split. Fragments are loaded DIRECTLY
// from global in fragment order: lane (m=lane&31, kh=lane>>5) reads
// row0+m, bytes [k0 .. k0+32). Lanes m and m+32 cover adjacent 32B halves
// of the same row -> exactly 32 x 64B lines per wave per chunk (fully
// line-efficient). This deletes the old per-chunk LDS round-trip
// (ds_write+ds_read+lgkm waits) from the critical path.
// Cross-wave K-reduce: all 4 waves dump 16 partials to LDS, then each
// wave reduces + stores 4 of the 16 q's (parallel tail, not wave0-serial).

#define B_SZ 1024
#define HID 512
#define IN_D 768
#define OUT_D 256
#define NK 8

typedef float floatx16 __attribute__((ext_vector_type(16)));
typedef short short8  __attribute__((ext_vector_type(8)));

// round-half-up fp32->bf16 pair pack (low16 = a, high16 = b)
__device__ __forceinline__ unsigned pack_bf16(float a, float b) {
    unsigned ua = __float_as_uint(a) + 0x8000u;
    unsigned ub = __float_as_uint(b) + 0x8000u;
    return __builtin_amdgcn_perm(ub, ua, 0x07060302);
}
__device__ __forceinline__ uint4 pack8(float4 lo, float4 hi) {
    uint4 v;
    v.x = pack_bf16(lo.x, lo.y); v.y = pack_bf16(lo.z, lo.w);
    v.z = pack_bf16(hi.x, hi.y); v.w = pack_bf16(hi.z, hi.w);
    return v;
}

// One 32x32 C tile per block; 4 waves split K (nch 16-wide chunks each).
template<bool A_BF16>
__device__ __forceinline__ void gemm32_direct(
    const void* Aip, const float* __restrict__ Wp,
    const float* __restrict__ bias, float* __restrict__ C,
    int N, int K, int nch, int row0, int col0,
    float (*__restrict__ redf)[64])
{
    const int tid  = threadIdx.x;
    const int w    = tid >> 6;
    const int lane = tid & 63;
    const int m    = lane & 31;
    const int kh   = lane >> 5;
    const int k0   = w * nch * 16 + kh * 8;

    const float* pw = Wp + (size_t)(col0 + m) * K + k0;
    float4 b0 = *(const float4*)pw, b1 = *(const float4*)(pw + 4);

    floatx16 acc = {};

    if (A_BF16) {
        const __hip_bfloat16* pa =
            (const __hip_bfloat16*)Aip + (size_t)(row0 + m) * K + k0;
        uint4 av = *(const uint4*)pa;
        for (int c = 0; c < nch; ++c) {
            uint4 af = av;
            uint4 bf = pack8(b0, b1);
            if (c + 1 < nch) {                 // depth-1 prefetch
                pa += 16; pw += 16;
                av = *(const uint4*)pa;
                b0 = *(const float4*)pw; b1 = *(const float4*)(pw + 4);
            }
            acc = __builtin_amdgcn_mfma_f32_32x32x16_bf16(
                *(short8*)&af, *(short8*)&bf, acc, 0, 0, 0);
        }
    } else {
        const float* pa = (const float*)Aip + (size_t)(row0 + m) * K + k0;
        float4 a0 = *(const float4*)pa, a1 = *(const float4*)(pa + 4);
        for (int c = 0; c < nch; ++c) {
            uint4 af = pack8(a0, a1);
            uint4 bf = pack8(b0, b1);
            if (c + 1 < nch) {                 // depth-1 prefetch
                pa += 16; pw += 16;
                a0 = *(const float4*)pa; a1 = *(const float4*)(pa + 4);
                b0 = *(const float4*)pw; b1 = *(const float4*)(pw + 4);
            }
            acc = __builtin_amdgcn_mfma_f32_32x32x16_bf16(
                *(short8*)&af, *(short8*)&bf, acc, 0, 0, 0);
        }
    }

    // cross-wave K reduction, parallel tail: all waves dump, wave w
    // reduces + stores q = 4w..4w+3.
    #pragma unroll
    for (int q = 0; q < 16; ++q) redf[w * 16 + q][lane] = acc[q];
    __syncthreads();

    // C/D layout (m74/m101): col = lane&31, row = (q&3)+8*(q>>2)+4*(lane>>5)
    // For q = 4w+i: row = i + 8w + 4kh.
    const int ccol = col0 + m;
    const float bv = bias[ccol];
    float* cb = C + (size_t)(row0 + 8 * w + 4 * kh) * N + ccol;
    #pragma unroll
    for (int i = 0; i < 4; ++i) {
        const int q = 4 * w + i;
        float s = redf[q][lane] + redf[16 + q][lane]
                + redf[32 + q][lane] + redf[48 + q][lane];
        cb[(size_t)i * N] = s + bv;            // 128B coalesced store
    }
}

// fused c & t: blocks 0..511 -> c (K=768, 12 chunks/wave), 512..1023 -> t (8)
__global__ __launch_bounds__(256) void gemm_ct_k(
    const float* __restrict__ combin, const float* __restrict__ W2,
    const float* __restrict__ b2, float* __restrict__ c_emb,
    const float* __restrict__ s_emb, const float* __restrict__ W1,
    const float* __restrict__ b1, float* __restrict__ t_emb)
{
    __shared__ float redf[64][64];   // 16 KB
    int id = blockIdx.x;
    if (id < 512) {
        gemm32_direct<false>(combin, W2, b2, c_emb, HID, IN_D, 12,
                             (id >> 4) * 32, (id & 15) * 32, redf);
    } else {
        id -= 512;
        gemm32_direct<false>(s_emb, W1, b1, t_emb, HID, HID, 8,
                             (id >> 4) * 32, (id & 15) * 32, redf);
    }
}

// out = o2(bf16) @ W3^T + b3 : 256 blocks (32 m x 8 n), K=512 -> 8 chunks/wave
__global__ __launch_bounds__(256) void gemm_out_k(
    const __hip_bfloat16* __restrict__ o2, const float* __restrict__ W3,
    const float* __restrict__ b3, float* __restrict__ out)
{
    __shared__ float redf[64][64];   // 16 KB
    int id = blockIdx.x;
    gemm32_direct<true>(o2, W3, b3, out, OUT_D, HID, 8,
                        (id >> 3) * 32, (id & 7) * 32, redf);
}

// Taylor attention: one block per batch. Moments m_k = sum_j t^k v,
// p_k = sum_j t^k (k=0..7) via LDS-transpose reduction, then per-row
// degree-7 Horner in a_i. Output o2 in bf16 (pre-packed for gemm_out).
__global__ __launch_bounds__(256) void attn_taylor(
    const float* __restrict__ c_emb, const float* __restrict__ t_emb,
    const float* __restrict__ s_emb, unsigned* __restrict__ o2u)
{
    __shared__ float t_s[HID];
    __shared__ float v_s[HID];
    __shared__ float part[256][17];   // [thread][p0..p7,m0..m7], +1 pad
    __shared__ float red2[16][16];
    __shared__ float fin[16];

    const int b = blockIdx.x, tid = threadIdx.x;

    if (tid < 128) ((float4*)t_s)[tid] = ((const float4*)(t_emb + (size_t)b * HID))[tid];
    else           ((float4*)v_s)[tid - 128] = ((const float4*)(s_emb + (size_t)b * HID))[tid - 128];
    float2 cc = ((const float2*)(c_emb + (size_t)b * HID))[tid];
    __syncthreads();

    float2 tt = ((float2*)t_s)[tid];
    float2 vv = ((float2*)v_s)[tid];
    float tp0 = 1.f, tp1 = 1.f;
    #pragma unroll
    for (int k = 0; k < NK; ++k) {
        part[tid][k]      = tp0 + tp1;
        part[tid][k + NK] = fmaf(tp0, vv.x, tp1 * vv.y);
        tp0 *= tt.x; tp1 *= tt.y;
    }
    __syncthreads();
    {   // 256 threads = 16 moments x 16 row-groups
        int k = tid & 15, g = tid >> 4;
        float s = 0.f;
        #pragma unroll
        for (int r = 0; r < 16; ++r) s += part[g * 16 + r][k];
        red2[g][k] = s;
    }
    __syncthreads();
    if (tid < 16) {
        float s = 0.f;
        #pragma unroll
        for (int g = 0; g < 16; ++g) s += red2[g][tid];
        fin[tid] = s;
    }
    __syncthreads();

    const float invf[NK] = {1.f, 1.f, 0.5f, 1.f / 6.f, 1.f / 24.f,
                            1.f / 120.f, 1.f / 720.f, 1.f / 5040.f};
    float cp[NK], cm[NK];
    #pragma unroll
    for (int k = 0; k < NK; ++k) {
        cp[k] = fin[k] * invf[k];
        cm[k] = fin[k + NK] * invf[k];
    }

    const float scale = 0.04419417382415922f;  // 1/sqrt(512)
    float a0 = scale * cc.x, a1 = scale * cc.y;
    float n0 = cm[NK - 1], d0 = cp[NK - 1], n1 = cm[NK - 1], d1 = cp[NK - 1];
    #pragma unroll
    for (int k = NK - 2; k >= 0; --k) {
        n0 = fmaf(n0, a0, cm[k]); d0 = fmaf(d0, a0, cp[k]);
        n1 = fmaf(n1, a1, cm[k]); d1 = fmaf(d1, a1, cp[k]);
    }
    float r0 = n0 * __builtin_amdgcn_rcpf(d0);
    float r1 = n1 * __builtin_amdgcn_rcpf(d1);
    r0 = r0 > 0.f ? r0 : 0.f;
    r1 = r1 > 0.f ? r1 : 0.f;
    // rows 2*tid, 2*tid+1 -> one packed dword, coalesced
    o2u[(size_t)b * (HID / 2) + tid] = pack_bf16(r0, r1);
}

extern "C" void kernel_launch(void* const* d_in, const int* in_sizes, int n_in,
                              void* d_out, int out_size, void* d_ws, size_t ws_size,
                              hipStream_t stream)
{
    const float* combin = (const float*)d_in[0];
    const float* s_emb  = (const float*)d_in[1];
    const float* W1     = (const float*)d_in[2];
    const float* b1     = (const float*)d_in[3];
    const float* W2     = (const float*)d_in[4];
    const float* b2     = (const float*)d_in[5];
    const float* W3     = (const float*)d_in[6];
    const float* b3     = (const float*)d_in[7];
    float* out = (float*)d_out;

    float* ws = (float*)d_ws;
    float* c_emb = ws;                            // [B, HID] fp32
    float* t_emb = ws + (size_t)B_SZ * HID;       // [B, HID] fp32
    unsigned* o2u = (unsigned*)(ws + (size_t)2 * B_SZ * HID);  // [B, HID] bf16

    gemm_ct_k<<<1024, 256, 0, stream>>>(combin, W2, b2, c_emb, s_emb, W1, b1, t_emb);
    attn_taylor<<<B_SZ, 256, 0, stream>>>(c_emb, t_emb, s_emb, o2u);
    gemm_out_k<<<256, 256, 0, stream>>>((const __hip_bfloat16*)o2u, W3, b3, out);
}